// Round 8
// baseline (147.682 us; speedup 1.0000x reference)
//
#include <hip/hip_runtime.h>

#define SS 1024
#define BB 4096
#define HH 8
#define XSTRIDE (BB * HH)          // floats per timestep slice
#define GBYTES (8 * XSTRIDE * 4)   // bytes per 8-step group (1 MiB)

typedef float f32x2 __attribute__((ext_vector_type(2)));

// DPP cross-lane (VALU pipe): xor1/2/3 via quad_perm, xor7 via row_half_mirror.
__device__ __forceinline__ int dpp_x1(int v) { return __builtin_amdgcn_mov_dpp(v, 0xB1, 0xF, 0xF, true); }
__device__ __forceinline__ int dpp_x2(int v) { return __builtin_amdgcn_mov_dpp(v, 0x4E, 0xF, 0xF, true); }
__device__ __forceinline__ int dpp_x3(int v) { return __builtin_amdgcn_mov_dpp(v, 0x1B, 0xF, 0xF, true); }
__device__ __forceinline__ int dpp_x7(int v) { return __builtin_amdgcn_mov_dpp(v, 0x141, 0xF, 0xF, true); }

// Butterfly register m holds h[j ^ MK[m]]; h-side weights pre-permuted to match.
__device__ __constant__ int MK_[8] = {0, 1, 2, 3, 7, 6, 5, 4};

// SADDR-form pinned load: 32-bit VGPR offset + SGPR64 base. Pinned (volatile)
// so neither scheduler nor RA can sink it (rounds 2-6: C loads always sank).
#define ALOADS(DST, OFF) \
    asm volatile("global_load_dwordx4 %0, %1, %2" : "=v"(DST) : "v"(OFF), "s"(x))

// Counted wait; sched_barrier stops register-use hoisting past the waitcnt
// (guide rule 18) and pins program order around it.
#define WAITV(N) do {                                                                  \
    asm volatile("s_waitcnt vmcnt(" #N ")" ::: "memory");                              \
    __builtin_amdgcn_sched_barrier(0);                                                 \
} while (0)

// X-phase for one step (full): input-side pre-activations. Weights/biases
// PRE-SCALED: r/z rows by -log2(e), n rows by +2*log2(e).
#define XFULL(BUF, V) do {                                                             \
    const float4 Xa_ = BUF[2 * (V)], Xb_ = BUF[2 * (V) + 1];                           \
    f32x2 a0_ = {Xa_.x, Xa_.y}, a1_ = {Xa_.z, Xa_.w};                                  \
    f32x2 a2_ = {Xb_.x, Xb_.y}, a3_ = {Xb_.z, Xb_.w};                                  \
    f32x2 sr_ = {bias_r, 0.0f}, sz_ = {bias_z, 0.0f}, sn_ = {bni_s, 0.0f};             \
    sr_ = __builtin_elementwise_fma(a0_, wri[0], sr_);                                 \
    sz_ = __builtin_elementwise_fma(a0_, wzi[0], sz_);                                 \
    sn_ = __builtin_elementwise_fma(a0_, wni[0], sn_);                                 \
    sr_ = __builtin_elementwise_fma(a1_, wri[1], sr_);                                 \
    sz_ = __builtin_elementwise_fma(a1_, wzi[1], sz_);                                 \
    sn_ = __builtin_elementwise_fma(a1_, wni[1], sn_);                                 \
    sr_ = __builtin_elementwise_fma(a2_, wri[2], sr_);                                 \
    sz_ = __builtin_elementwise_fma(a2_, wzi[2], sz_);                                 \
    sn_ = __builtin_elementwise_fma(a2_, wni[2], sn_);                                 \
    sr_ = __builtin_elementwise_fma(a3_, wri[3], sr_);                                 \
    sz_ = __builtin_elementwise_fma(a3_, wzi[3], sz_);                                 \
    sn_ = __builtin_elementwise_fma(a3_, wni[3], sn_);                                 \
    xr[(V)] = sr_.x + sr_.y; xz[(V)] = sz_.x + sz_.y; xn[(V)] = sn_.x + sn_.y;         \
} while (0)

// One 8-step group. Steps 0..5 weave X(u+2) into the R-chain's stall windows;
// steps 6..7 weave the NEXT-NEXT group's 16 loads (into this same, now-free
// buffer) through the same fill sites. DL=0 variants (epilogue) skip loads.
#define GROUP(BUF, SBASE, DL) do {                                                     \
    XFULL(BUF, 0);                                                                     \
    XFULL(BUF, 1);                                                                     \
    _Pragma("unroll")                                                                  \
    for (int u = 0; u < 8; ++u) {                                                      \
        const int k0 = (u >= 6) ? (u - 6) * 8 : 0;                                     \
        /* R-dots split into two 2-deep pk chains + pk_add (shorter chain) */          \
        f32x2 rA = {xr[u], 0.0f}, zA = {xz[u], 0.0f}, nA = {bnh_s, 0.0f};              \
        f32x2 rB = {0.0f, 0.0f}, zB = {0.0f, 0.0f}, nB = {0.0f, 0.0f};                 \
        rA = __builtin_elementwise_fma(hv2[0], wrh[0], rA);                            \
        zA = __builtin_elementwise_fma(hv2[0], wzh[0], zA);                            \
        nA = __builtin_elementwise_fma(hv2[0], wnh[0], nA);                            \
        rB = __builtin_elementwise_fma(hv2[2], wrh[2], rB);                            \
        zB = __builtin_elementwise_fma(hv2[2], wzh[2], zB);                            \
        nB = __builtin_elementwise_fma(hv2[2], wnh[2], nB);                            \
        rA = __builtin_elementwise_fma(hv2[1], wrh[1], rA);                            \
        zA = __builtin_elementwise_fma(hv2[1], wzh[1], zA);                            \
        nA = __builtin_elementwise_fma(hv2[1], wnh[1], nA);                            \
        rB = __builtin_elementwise_fma(hv2[3], wrh[3], rB);                            \
        zB = __builtin_elementwise_fma(hv2[3], wzh[3], zB);                            \
        nB = __builtin_elementwise_fma(hv2[3], wnh[3], nB);                            \
        rA = rA + rB; zA = zA + zB; nA = nA + nB;                                      \
        const float srr = rA.x + rA.y;                                                 \
        const float szz = zA.x + zA.y;                                                 \
        const float snn = nA.x + nA.y;                                                 \
        const bool W = (u + 2 < 8);                                                    \
        f32x2 sr_, sz_, sn_;                                                           \
        if (W) {   /* X(u+2) part 1 */                                                 \
            const float4 Xa_ = BUF[2 * (u + 2)];                                       \
            f32x2 a0_ = {Xa_.x, Xa_.y}, a1_ = {Xa_.z, Xa_.w};                          \
            sr_ = (f32x2){bias_r, 0.0f}; sz_ = (f32x2){bias_z, 0.0f};                  \
            sn_ = (f32x2){bni_s, 0.0f};                                                \
            sr_ = __builtin_elementwise_fma(a0_, wri[0], sr_);                         \
            sz_ = __builtin_elementwise_fma(a0_, wzi[0], sz_);                         \
            sn_ = __builtin_elementwise_fma(a0_, wni[0], sn_);                         \
            sr_ = __builtin_elementwise_fma(a1_, wri[1], sr_);                         \
            sz_ = __builtin_elementwise_fma(a1_, wzi[1], sz_);                         \
            sn_ = __builtin_elementwise_fma(a1_, wni[1], sn_);                         \
        } else if (DL) {                                                               \
            ALOADS(BUF[k0 + 0], off[k0 + 0]);                                          \
            ALOADS(BUF[k0 + 1], off[k0 + 1]);                                          \
            ALOADS(BUF[k0 + 2], off[k0 + 2]);                                          \
        }                                                                              \
        const float er = __builtin_amdgcn_exp2f(srr);                                  \
        const float ez = __builtin_amdgcn_exp2f(szz);                                  \
        if (W) {   /* X(u+2) part 2 */                                                 \
            const float4 Xb_ = BUF[2 * (u + 2) + 1];                                   \
            f32x2 a2_ = {Xb_.x, Xb_.y}, a3_ = {Xb_.z, Xb_.w};                          \
            sr_ = __builtin_elementwise_fma(a2_, wri[2], sr_);                         \
            sz_ = __builtin_elementwise_fma(a2_, wzi[2], sz_);                         \
            sn_ = __builtin_elementwise_fma(a2_, wni[2], sn_);                         \
            sr_ = __builtin_elementwise_fma(a3_, wri[3], sr_);                         \
            sz_ = __builtin_elementwise_fma(a3_, wzi[3], sz_);                         \
            sn_ = __builtin_elementwise_fma(a3_, wni[3], sn_);                         \
        } else if (DL) {                                                               \
            ALOADS(BUF[k0 + 3], off[k0 + 3]);                                          \
            ALOADS(BUF[k0 + 4], off[k0 + 4]);                                          \
            ALOADS(BUF[k0 + 5], off[k0 + 5]);                                          \
        }                                                                              \
        const float r_ = __builtin_amdgcn_rcpf(1.0f + er);                             \
        const float z_ = __builtin_amdgcn_rcpf(1.0f + ez);                             \
        if (W) {   /* X(u+2) reduce */                                                 \
            xr[u + 2] = sr_.x + sr_.y;                                                 \
            xz[u + 2] = sz_.x + sz_.y;                                                 \
            xn[u + 2] = sn_.x + sn_.y;                                                 \
        } else if (DL) {                                                               \
            ALOADS(BUF[k0 + 6], off[k0 + 6]);                                          \
            ALOADS(BUF[k0 + 7], off[k0 + 7]);                                          \
        }                                                                              \
        const float en = __builtin_amdgcn_exp2f(fmaf(r_, snn, xn[u]));                 \
        const float n_ = fmaf(-2.0f, __builtin_amdgcn_rcpf(1.0f + en), 1.0f);          \
        h = n_ + z_ * (h - n_);                                                        \
        const int hb_ = __float_as_int(h);                                             \
        const int t1_ = dpp_x1(hb_);   /* h[j^1] */                                    \
        const int t2_ = dpp_x2(hb_);   /* h[j^2] */                                    \
        const int t3_ = dpp_x3(hb_);   /* h[j^3] (direct, depth-1) */                  \
        const int t4_ = dpp_x7(hb_);   /* h[j^7] */                                    \
        const int t5_ = dpp_x7(t1_);   /* h[j^6] */                                    \
        const int t6_ = dpp_x7(t2_);   /* h[j^5] */                                    \
        const int t7_ = dpp_x7(t3_);   /* h[j^4] (depth-2) */                          \
        hv2[0] = (f32x2){h, __int_as_float(t1_)};                                      \
        hv2[1] = (f32x2){__int_as_float(t2_), __int_as_float(t3_)};                    \
        hv2[2] = (f32x2){__int_as_float(t4_), __int_as_float(t5_)};                    \
        hv2[3] = (f32x2){__int_as_float(t6_), __int_as_float(t7_)};                    \
        __builtin_nontemporal_store(h, &op[(size_t)((SBASE) + u) * XSTRIDE]);          \
    }                                                                                  \
    if (DL) {                                                                          \
        _Pragma("unroll")                                                              \
        for (int k_ = 0; k_ < 16; ++k_) off[k_] += GBYTES;                             \
    }                                                                                  \
} while (0)

// Prologue staging: 16 pinned loads of one group + offset advance.
#define LOADGP(BUF) do {                                                               \
    _Pragma("unroll")                                                                  \
    for (int k_ = 0; k_ < 16; ++k_) ALOADS(BUF[k_], off[k_]);                          \
    _Pragma("unroll")                                                                  \
    for (int k_ = 0; k_ < 16; ++k_) off[k_] += GBYTES;                                 \
} while (0)

// 8 lanes per batch element (lane j = hidden index), 8 batches per wave,
// 512 waves (2/CU, 0.5/SIMD). waves_per_eu(1,1) tells the allocator only one
// wave/EU will run -> full 512-VGPR budget, no AGPR shuffling of the pinned
// prefetch buffers (round 7's VGPR_Count=128 was the smoking gun).
__global__ __launch_bounds__(64) __attribute__((amdgpu_waves_per_eu(1, 1)))
void gru_kernel(
    const float* __restrict__ x,
    const float* __restrict__ w_ih,
    const float* __restrict__ w_hh,
    const float* __restrict__ b_ih,
    const float* __restrict__ b_hh,
    float* __restrict__ out)
{
    const int lane = threadIdx.x;
    const int j = lane & 7;
    const int bg = (blockIdx.x << 3) + (lane >> 3);

    const float SR = -1.4426950408889634f;     // -log2(e): sigmoid scale
    const float SN = 2.8853900817779268f;      // 2*log2(e): tanh scale

    f32x2 wri[4], wzi[4], wni[4];
    #pragma unroll
    for (int p = 0; p < 4; ++p) {
        wri[p] = (f32x2){SR * w_ih[j * 8 + 2 * p],        SR * w_ih[j * 8 + 2 * p + 1]};
        wzi[p] = (f32x2){SR * w_ih[(8 + j) * 8 + 2 * p],  SR * w_ih[(8 + j) * 8 + 2 * p + 1]};
        wni[p] = (f32x2){SN * w_ih[(16 + j) * 8 + 2 * p], SN * w_ih[(16 + j) * 8 + 2 * p + 1]};
    }
    f32x2 wrh[4], wzh[4], wnh[4];
    #pragma unroll
    for (int p = 0; p < 4; ++p) {
        const int c0 = j ^ MK_[2 * p], c1 = j ^ MK_[2 * p + 1];
        wrh[p] = (f32x2){SR * w_hh[j * 8 + c0],        SR * w_hh[j * 8 + c1]};
        wzh[p] = (f32x2){SR * w_hh[(8 + j) * 8 + c0],  SR * w_hh[(8 + j) * 8 + c1]};
        wnh[p] = (f32x2){SN * w_hh[(16 + j) * 8 + c0], SN * w_hh[(16 + j) * 8 + c1]};
    }
    const float bias_r = SR * (b_ih[j] + b_hh[j]);
    const float bias_z = SR * (b_ih[8 + j] + b_hh[8 + j]);
    const float bni_s  = SN * b_ih[16 + j];
    const float bnh_s  = SN * b_hh[16 + j];

    float* op = out + (size_t)bg * HH + j;
    float* hlast = out + (size_t)SS * BB * HH + (size_t)bg * HH + j;

    // 32-bit byte offsets into x (max ~134 MB < 2^31), advanced 1 MiB/group.
    int off[16];
    #pragma unroll
    for (int k = 0; k < 16; ++k)
        off[k] = bg * (HH * 4) + (k >> 1) * (XSTRIDE * 4) + (k & 1) * 16;

    float4 xA[16], xB[16];

    // prologue: groups 0 -> A, 1 -> B; retire A's 16 (B's stay in flight)
    LOADGP(xA);
    LOADGP(xB);
    WAITV(16);

    float h = 0.0f;
    f32x2 hv2[4] = {{0,0},{0,0},{0,0},{0,0}};
    float xr[8], xz[8], xn[8];

    // Steady state at each WAITV(24): newest 24 = this group's 16 woven loads
    // + 8 stores; everything older (incl. next group's buffer loads) retired.
    for (int g = 0; g < 124; g += 2) {
        GROUP(xA, g * 8, 1);
        WAITV(24);
        GROUP(xB, (g + 1) * 8, 1);
        WAITV(24);
    }
    GROUP(xA, 124 * 8, 1);   // weaves loads for group 126 -> A
    WAITV(24);
    GROUP(xB, 125 * 8, 1);   // weaves loads for group 127 -> B
    WAITV(24);
    GROUP(xA, 126 * 8, 0);
    WAITV(8);
    GROUP(xB, 127 * 8, 0);

    *hlast = h;
}

extern "C" void kernel_launch(void* const* d_in, const int* in_sizes, int n_in,
                              void* d_out, int out_size, void* d_ws, size_t ws_size,
                              hipStream_t stream) {
    const float* x    = (const float*)d_in[0];
    const float* w_ih = (const float*)d_in[1];
    const float* w_hh = (const float*)d_in[2];
    const float* b_ih = (const float*)d_in[3];
    const float* b_hh = (const float*)d_in[4];
    float* out = (float*)d_out;
    gru_kernel<<<BB / 8, 64, 0, stream>>>(x, w_ih, w_hh, b_ih, b_hh, out);
}

// Round 9
// 140.930 us; speedup vs baseline: 1.0479x; 1.0479x over previous
//
#include <hip/hip_runtime.h>

#define SS 1024
#define BB 4096
#define HH 8
#define XSTRIDE (BB * HH)   // floats per timestep slice

typedef float f32x2 __attribute__((ext_vector_type(2)));

// DPP cross-lane (VALU pipe): xor1/xor2 via quad_perm, xor7 via row_half_mirror.
__device__ __forceinline__ int dpp_x1(int v) { return __builtin_amdgcn_mov_dpp(v, 0xB1, 0xF, 0xF, true); }
__device__ __forceinline__ int dpp_x2(int v) { return __builtin_amdgcn_mov_dpp(v, 0x4E, 0xF, 0xF, true); }
__device__ __forceinline__ int dpp_x7(int v) { return __builtin_amdgcn_mov_dpp(v, 0x141, 0xF, 0xF, true); }

// Butterfly register m holds h[j ^ MK[m]]; h-side weights pre-permuted to match.
__device__ __constant__ int MK_[8] = {0, 1, 2, 3, 7, 6, 5, 4};

// Pinned prefetch: inline-asm load cannot be sunk by the scheduler/RA.
#define ALOAD(DST, PTR) asm volatile("global_load_dwordx4 %0, %1, off" : "=v"(DST) : "v"(PTR))

#define WAITV(N) do {                                                                  \
    asm volatile("s_waitcnt vmcnt(" #N ")" ::: "memory");                              \
    __builtin_amdgcn_sched_barrier(0);                                                 \
} while (0)

// Scheduling fence: nothing crosses. Used to FORCE the weave (LLVM otherwise
// re-clusters the filler ops away from the stall windows they must fill).
#define SB() __builtin_amdgcn_sched_barrier(0)

// X pre-activations for one step (head steps 0,1 of each group).
// Weights/biases PRE-SCALED: r/z rows by -log2(e), n rows by +2*log2(e).
#define XFULL(BUF, V) do {                                                             \
    const float4 Xa_ = BUF[2 * (V)], Xb_ = BUF[2 * (V) + 1];                           \
    f32x2 a0_ = {Xa_.x, Xa_.y}, a1_ = {Xa_.z, Xa_.w};                                  \
    f32x2 a2_ = {Xb_.x, Xb_.y}, a3_ = {Xb_.z, Xb_.w};                                  \
    f32x2 sr_ = {bias_r, 0.0f}, sz_ = {bias_z, 0.0f}, sn_ = {bni_s, 0.0f};             \
    sr_ = __builtin_elementwise_fma(a0_, wri[0], sr_);                                 \
    sz_ = __builtin_elementwise_fma(a0_, wzi[0], sz_);                                 \
    sn_ = __builtin_elementwise_fma(a0_, wni[0], sn_);                                 \
    sr_ = __builtin_elementwise_fma(a1_, wri[1], sr_);                                 \
    sz_ = __builtin_elementwise_fma(a1_, wzi[1], sz_);                                 \
    sn_ = __builtin_elementwise_fma(a1_, wni[1], sn_);                                 \
    sr_ = __builtin_elementwise_fma(a2_, wri[2], sr_);                                 \
    sz_ = __builtin_elementwise_fma(a2_, wzi[2], sz_);                                 \
    sn_ = __builtin_elementwise_fma(a2_, wni[2], sn_);                                 \
    sr_ = __builtin_elementwise_fma(a3_, wri[3], sr_);                                 \
    sz_ = __builtin_elementwise_fma(a3_, wzi[3], sz_);                                 \
    sn_ = __builtin_elementwise_fma(a3_, wni[3], sn_);                                 \
    xr[(V)] = sr_.x + sr_.y; xz[(V)] = sz_.x + sz_.y; xn[(V)] = sn_.x + sn_.y;         \
} while (0)

// One 8-step group. SB()-sliced static schedule per step:
//   S1 h-dots | F1 | S2 exp(r,z) | F2 | S3 rcp(r,z) | F3 | S4-S6 n-path+update.
// Fillers F1-F3: steps 0..5 -> X(u+2) in three parts; steps 6,7 -> the 16
// pinned loads of group LGRP into this (now dead) buffer.
#define GROUP(BUF, SBASE, LGRP, DL) do {                                               \
    const float* lp_ = xp + (size_t)(LGRP) * 8 * XSTRIDE;                              \
    XFULL(BUF, 0);                                                                     \
    XFULL(BUF, 1);                                                                     \
    _Pragma("unroll")                                                                  \
    for (int u = 0; u < 8; ++u) {                                                      \
        /* S1: h-side dots (12 pk_fma, 3 independent 4-deep chains) */                 \
        f32x2 hr2 = {xr[u], 0.0f}, hz2 = {xz[u], 0.0f}, hn2 = {bnh_s, 0.0f};           \
        _Pragma("unroll")                                                              \
        for (int p_ = 0; p_ < 4; ++p_) {                                               \
            hr2 = __builtin_elementwise_fma(hv2[p_], wrh[p_], hr2);                    \
            hz2 = __builtin_elementwise_fma(hv2[p_], wzh[p_], hz2);                    \
            hn2 = __builtin_elementwise_fma(hv2[p_], wnh[p_], hn2);                    \
        }                                                                              \
        const float srr = hr2.x + hr2.y;                                               \
        const float szz = hz2.x + hz2.y;                                               \
        const float snn = hn2.x + hn2.y;                                               \
        SB();                                                                          \
        const bool W = (u + 2 < 8);                                                    \
        const int k0 = (u >= 6) ? (u - 6) * 8 : 0;                                     \
        f32x2 sr_, sz_, sn_;                                                           \
        /* F1: X(u+2) part1  /  loads k0+0..2 */                                       \
        if (W) {                                                                       \
            const float4 Xa_ = BUF[2 * (u + 2)];                                       \
            f32x2 a0_ = {Xa_.x, Xa_.y}, a1_ = {Xa_.z, Xa_.w};                          \
            sr_ = (f32x2){bias_r, 0.0f}; sz_ = (f32x2){bias_z, 0.0f};                  \
            sn_ = (f32x2){bni_s, 0.0f};                                                \
            sr_ = __builtin_elementwise_fma(a0_, wri[0], sr_);                         \
            sz_ = __builtin_elementwise_fma(a0_, wzi[0], sz_);                         \
            sn_ = __builtin_elementwise_fma(a0_, wni[0], sn_);                         \
            sr_ = __builtin_elementwise_fma(a1_, wri[1], sr_);                         \
            sz_ = __builtin_elementwise_fma(a1_, wzi[1], sz_);                         \
            sn_ = __builtin_elementwise_fma(a1_, wni[1], sn_);                         \
        } else if (DL) {                                                               \
            ALOAD(BUF[k0 + 0], lp_ + (size_t)((k0 + 0) >> 1) * XSTRIDE + ((k0 + 0) & 1) * 4); \
            ALOAD(BUF[k0 + 1], lp_ + (size_t)((k0 + 1) >> 1) * XSTRIDE + ((k0 + 1) & 1) * 4); \
            ALOAD(BUF[k0 + 2], lp_ + (size_t)((k0 + 2) >> 1) * XSTRIDE + ((k0 + 2) & 1) * 4); \
        }                                                                              \
        SB();                                                                          \
        /* S2: r/z exponentials */                                                     \
        const float er = __builtin_amdgcn_exp2f(srr);                                  \
        const float ez = __builtin_amdgcn_exp2f(szz);                                  \
        SB();                                                                          \
        /* F2: X(u+2) part2  /  loads k0+3..5 */                                       \
        if (W) {                                                                       \
            const float4 Xb_ = BUF[2 * (u + 2) + 1];                                   \
            f32x2 a2_ = {Xb_.x, Xb_.y}, a3_ = {Xb_.z, Xb_.w};                          \
            sr_ = __builtin_elementwise_fma(a2_, wri[2], sr_);                         \
            sz_ = __builtin_elementwise_fma(a2_, wzi[2], sz_);                         \
            sn_ = __builtin_elementwise_fma(a2_, wni[2], sn_);                         \
            sr_ = __builtin_elementwise_fma(a3_, wri[3], sr_);                         \
            sz_ = __builtin_elementwise_fma(a3_, wzi[3], sz_);                         \
            sn_ = __builtin_elementwise_fma(a3_, wni[3], sn_);                         \
        } else if (DL) {                                                               \
            ALOAD(BUF[k0 + 3], lp_ + (size_t)((k0 + 3) >> 1) * XSTRIDE + ((k0 + 3) & 1) * 4); \
            ALOAD(BUF[k0 + 4], lp_ + (size_t)((k0 + 4) >> 1) * XSTRIDE + ((k0 + 4) & 1) * 4); \
            ALOAD(BUF[k0 + 5], lp_ + (size_t)((k0 + 5) >> 1) * XSTRIDE + ((k0 + 5) & 1) * 4); \
        }                                                                              \
        SB();                                                                          \
        /* S3: r/z reciprocals */                                                      \
        const float r_ = __builtin_amdgcn_rcpf(1.0f + er);                             \
        const float z_ = __builtin_amdgcn_rcpf(1.0f + ez);                             \
        SB();                                                                          \
        /* F3: X(u+2) reduce  /  loads k0+6..7 */                                      \
        if (W) {                                                                       \
            xr[u + 2] = sr_.x + sr_.y;                                                 \
            xz[u + 2] = sz_.x + sz_.y;                                                 \
            xn[u + 2] = sn_.x + sn_.y;                                                 \
        } else if (DL) {                                                               \
            ALOAD(BUF[k0 + 6], lp_ + (size_t)((k0 + 6) >> 1) * XSTRIDE + ((k0 + 6) & 1) * 4); \
            ALOAD(BUF[k0 + 7], lp_ + (size_t)((k0 + 7) >> 1) * XSTRIDE + ((k0 + 7) & 1) * 4); \
        }                                                                              \
        SB();                                                                          \
        /* S4-S6: n path, h update, butterfly, store */                                \
        const float en = __builtin_amdgcn_exp2f(fmaf(r_, snn, xn[u]));                 \
        const float n_ = fmaf(-2.0f, __builtin_amdgcn_rcpf(1.0f + en), 1.0f);          \
        h = n_ + z_ * (h - n_);                                                        \
        const int hb_ = __float_as_int(h);                                             \
        const int t1_ = dpp_x1(hb_);                                                   \
        const int t2_ = dpp_x2(hb_);                                                   \
        const int t3_ = dpp_x2(t1_);                                                   \
        const int t4_ = dpp_x7(hb_);                                                   \
        const int t5_ = dpp_x7(t1_);                                                   \
        const int t6_ = dpp_x7(t2_);                                                   \
        const int t7_ = dpp_x7(t3_);                                                   \
        hv2[0] = (f32x2){h, __int_as_float(t1_)};                                      \
        hv2[1] = (f32x2){__int_as_float(t2_), __int_as_float(t3_)};                    \
        hv2[2] = (f32x2){__int_as_float(t4_), __int_as_float(t5_)};                    \
        hv2[3] = (f32x2){__int_as_float(t6_), __int_as_float(t7_)};                    \
        __builtin_nontemporal_store(h, &op[(size_t)((SBASE) + u) * XSTRIDE]);          \
    }                                                                                  \
} while (0)

// Prologue staging: 16 pinned loads of one group.
#define LOADGP(BUF, GRP) do {                                                          \
    const float* bp_ = xp + (size_t)(GRP) * 8 * XSTRIDE;                               \
    _Pragma("unroll")                                                                  \
    for (int u_ = 0; u_ < 8; ++u_) {                                                   \
        const float* p_ = bp_ + (size_t)u_ * XSTRIDE;                                  \
        ALOAD(BUF[2 * u_],     p_);                                                    \
        ALOAD(BUF[2 * u_ + 1], p_ + 4);                                                \
    }                                                                                  \
} while (0)

// 8 lanes per batch element, 8 batches per wave, 512 waves.
__global__ __launch_bounds__(64, 1) void gru_kernel(
    const float* __restrict__ x,
    const float* __restrict__ w_ih,
    const float* __restrict__ w_hh,
    const float* __restrict__ b_ih,
    const float* __restrict__ b_hh,
    float* __restrict__ out)
{
    const int lane = threadIdx.x;
    const int j = lane & 7;
    const int bg = (blockIdx.x << 3) + (lane >> 3);

    const float SR = -1.4426950408889634f;     // -log2(e): sigmoid scale
    const float SN = 2.8853900817779268f;      // 2*log2(e): tanh scale

    f32x2 wri[4], wzi[4], wni[4];
    #pragma unroll
    for (int p = 0; p < 4; ++p) {
        wri[p] = (f32x2){SR * w_ih[j * 8 + 2 * p],        SR * w_ih[j * 8 + 2 * p + 1]};
        wzi[p] = (f32x2){SR * w_ih[(8 + j) * 8 + 2 * p],  SR * w_ih[(8 + j) * 8 + 2 * p + 1]};
        wni[p] = (f32x2){SN * w_ih[(16 + j) * 8 + 2 * p], SN * w_ih[(16 + j) * 8 + 2 * p + 1]};
    }
    f32x2 wrh[4], wzh[4], wnh[4];
    #pragma unroll
    for (int p = 0; p < 4; ++p) {
        const int c0 = j ^ MK_[2 * p], c1 = j ^ MK_[2 * p + 1];
        wrh[p] = (f32x2){SR * w_hh[j * 8 + c0],        SR * w_hh[j * 8 + c1]};
        wzh[p] = (f32x2){SR * w_hh[(8 + j) * 8 + c0],  SR * w_hh[(8 + j) * 8 + c1]};
        wnh[p] = (f32x2){SN * w_hh[(16 + j) * 8 + c0], SN * w_hh[(16 + j) * 8 + c1]};
    }
    float bias_r = SR * (b_ih[j] + b_hh[j]);
    float bias_z = SR * (b_ih[8 + j] + b_hh[8 + j]);
    float bni_s  = SN * b_ih[16 + j];
    float bnh_s  = SN * b_hh[16 + j];

    const float* xp = x + (size_t)bg * HH;
    float* op = out + (size_t)bg * HH + j;
    float* hlast = out + (size_t)SS * BB * HH + (size_t)bg * HH + j;

    float4 xA[16], xB[16];

    // prologue: groups 0 -> A, 1 -> B; retire A's 16 (B's stay in flight)
    LOADGP(xA, 0);
    LOADGP(xB, 1);
    WAITV(16);

    float h = 0.0f;
    f32x2 hv2[4] = {{0,0},{0,0},{0,0},{0,0}};
    float xr[8], xz[8], xn[8];

    for (int g = 0; g < 124; g += 2) {
        // VGPR-pin the 28 hot constants each iteration: forbids the RA from
        // banishing weights to AGPRs (round 7/8's VGPR_Count=128/132 proved
        // ~80 values were living outside the arch-VGPR file; accvgpr_read
        // copies before every pk_fma are the hidden per-step cost).
        asm volatile("" : "+v"(wri[0]), "+v"(wri[1]), "+v"(wri[2]), "+v"(wri[3]),
                          "+v"(wzi[0]), "+v"(wzi[1]), "+v"(wzi[2]), "+v"(wzi[3]),
                          "+v"(wni[0]), "+v"(wni[1]), "+v"(wni[2]), "+v"(wni[3]));
        asm volatile("" : "+v"(wrh[0]), "+v"(wrh[1]), "+v"(wrh[2]), "+v"(wrh[3]),
                          "+v"(wzh[0]), "+v"(wzh[1]), "+v"(wzh[2]), "+v"(wzh[3]),
                          "+v"(wnh[0]), "+v"(wnh[1]), "+v"(wnh[2]), "+v"(wnh[3]));
        asm volatile("" : "+v"(bias_r), "+v"(bias_z), "+v"(bni_s), "+v"(bnh_s));

        GROUP(xA, g * 8, g + 2, 1);
        WAITV(24);
        GROUP(xB, (g + 1) * 8, g + 3, 1);
        WAITV(24);
    }
    GROUP(xA, 992, 126, 1);    // weaves loads for group 126 -> xA
    WAITV(24);
    GROUP(xB, 1000, 127, 1);   // weaves loads for group 127 -> xB
    WAITV(24);
    GROUP(xA, 1008, 0, 0);
    WAITV(8);
    GROUP(xB, 1016, 0, 0);

    *hlast = h;
}

extern "C" void kernel_launch(void* const* d_in, const int* in_sizes, int n_in,
                              void* d_out, int out_size, void* d_ws, size_t ws_size,
                              hipStream_t stream) {
    const float* x    = (const float*)d_in[0];
    const float* w_ih = (const float*)d_in[1];
    const float* w_hh = (const float*)d_in[2];
    const float* b_ih = (const float*)d_in[3];
    const float* b_hh = (const float*)d_in[4];
    float* out = (float*)d_out;
    gru_kernel<<<BB / 8, 64, 0, stream>>>(x, w_ih, w_hh, b_ih, b_hh, out);
}